// Round 7
// baseline (189.116 us; speedup 1.0000x reference)
//
#include <hip/hip_runtime.h>

#define NSLOT 256

typedef double dbl4x __attribute__((ext_vector_type(4)));
typedef float  f32x4 __attribute__((ext_vector_type(4)));

// prep: zero the 16384 aux accumulation floats; transpose W to f64: wd2[k*32+o] = W[o][k]
__global__ __launch_bounds__(256) void prep_kernel(const float* __restrict__ W,
                                                   double* __restrict__ wd2,
                                                   float* __restrict__ ws) {
  int i = blockIdx.x * 256 + threadIdx.x;   // grid 64 -> 16384 threads
  ws[i] = 0.0f;
  if (i < 4096) {
    int k = i >> 5;
    int o = i & 31;
    wd2[i] = (double)W[(o << 7) + k];
  }
}

// ws layout: floats [0:8192) prob psum slots, [8192:16384) count slots; byte 65536+: Wt-f64 (32KB)
__global__ __launch_bounds__(512, 6) void moe_router_kernel(
    const float* __restrict__ x, const double* __restrict__ wd2,
    float* __restrict__ y, float* __restrict__ ws) {
  // Xs: 64 rows x 32 chunks of 16B, chunk XOR-swizzled: phys p holds logical d4 = p ^ (row&31)
  __shared__ float  Xs[64 * 128];     // 32 KB
  __shared__ double Ls[64 * 33];      // 16.9 KB  f64 logits, row-major, +1 pad

  const int tid = threadIdx.x;
  const int l   = tid & 63;                                  // lane
  const int wu  = __builtin_amdgcn_readfirstlane(tid >> 6);  // wave 0..7
  const int mtile = wu >> 1;                                 // 0..3 (16-row tile)
  const int ntile = wu & 1;                                  // 0..1 (16-col tile)
  const int c   = l & 15;                                    // M/N index within tile
  const int q   = l >> 4;                                    // k-slot 0..3
  const int bc  = blockIdx.x;                                // 0..8191
  const int b   = bc >> 10;
  const int c0  = (bc & 1023) << 1;                          // 2 tokens per block

  const float* xb = x + ((size_t)b * 32 * 2048 + c0) * 128;

  // ---- stage X via global_load_lds (linear LDS dest, pre-swizzled global src) ----
  {
    auto ldsX = (__attribute__((address_space(3))) char*)Xs;
    #pragma unroll
    for (int rep = 0; rep < 4; ++rep) {
      int i   = (rep << 9) + tid;           // 0..2047 = linear 16B chunk index
      int row = i >> 5;                     // 0..63
      int p   = i & 31;                     // physical chunk
      int h   = row & 31, t = row >> 5;
      int d4  = p ^ (row & 31);             // logical chunk stored at p
      const float* src = xb + ((size_t)h * 2048 + t) * 128 + (d4 << 2);
      __builtin_amdgcn_global_load_lds(
          (const __attribute__((address_space(1))) void*)src,
          (__attribute__((address_space(3))) void*)(ldsX + (size_t)i * 16),
          16, 0, 0);
    }
  }
  __syncthreads();

  // ---- phase B: 16x16 logit tile per wave via v_mfma_f64_16x16x4_f64, K=128 ----
  // A/B lane mapping (CDNA 16x16 pattern): A[i][k] i=l&15,k=l>>4; B[k][j] j=l&15,k=l>>4.
  const int rowA = (mtile << 4) + c;
  const int rsw  = rowA & 31;
  const int xbase = rowA << 7;
  const double* bp = wd2 + (q << 5) + (ntile << 4) + c;   // + t*128 per step
  dbl4x acc = {0.0, 0.0, 0.0, 0.0};
  #pragma unroll 8
  for (int t = 0; t < 32; ++t) {
    double a = (double)Xs[xbase + ((t ^ rsw) << 2) + q];  // logical k = 4t + q
    double bv = bp[t << 7];
    acc = __builtin_amdgcn_mfma_f64_16x16x4f64(a, bv, acc, 0, 0, 0);
  }

  // ---- C/D-layout-agnostic coordinate decode: E[i][j] = 33*i + j ----
  {
    double a1 = (q == 0) ? (double)(33 * c) : 0.0;   // A1[i][0] = 33 i
    double b1 = (q == 0) ? 1.0 : 0.0;                // B1[0][j] = 1
    double b2 = (q == 0) ? (double)c : 0.0;          // B2[0][j] = j
    dbl4x ecc = {0.0, 0.0, 0.0, 0.0};
    ecc = __builtin_amdgcn_mfma_f64_16x16x4f64(a1, b1, ecc, 0, 0, 0);
    ecc = __builtin_amdgcn_mfma_f64_16x16x4f64(b1, b2, ecc, 0, 0, 0);
    // whatever (i,j) this lane's acc[b] holds, ecc[b] = 33*i + j for the same element
    double* lbase = &Ls[((mtile << 4) * 33) + (ntile << 4)];
    lbase[(int)ecc[0]] = acc[0];
    lbase[(int)ecc[1]] = acc[1];
    lbase[(int)ecc[2]] = acc[2];
    lbase[(int)ecc[3]] = acc[3];
  }
  __syncthreads();

  // ---- softmax + top-2 for row l (redundant in every wave; lane = row) ----
  const double* lrow = &Ls[l * 33];
  double m1 = -1.0e300, m2 = -1.0e300;
  int    j1 = 0, j2 = 0;
  #pragma unroll
  for (int o = 0; o < 32; ++o) {
    double lv = lrow[o];
    if (lv > m1)      { m2 = m1; j2 = j1; m1 = lv; j1 = o; }
    else if (lv > m2) { m2 = lv; j2 = o; }
  }
  float S = 0.0f;
  #pragma unroll
  for (int o = 0; o < 32; ++o) S += __expf((float)(lrow[o] - m1));
  const float invS = 1.0f / S;
  const float p1 = invS;                               // exp(m1-m1)/S
  const float p2 = __expf((float)(m2 - m1)) * invS;
  const int   jpack = j1 | (j2 << 8);

  // ---- aux: this wave's 4-o slice of probs, shuffle-tree over 64 rows ----
  {
    float ps[4];
    #pragma unroll
    for (int j = 0; j < 4; ++j)
      ps[j] = __expf((float)(lrow[(wu << 2) + j] - m1)) * invS;
    #pragma unroll
    for (int m = 1; m < 64; m <<= 1) {
      #pragma unroll
      for (int j = 0; j < 4; ++j) ps[j] += __shfl_xor(ps[j], m, 64);
    }
    const int slot = (bc & (NSLOT - 1)) << 5;
    if (l == 0) {
      #pragma unroll
      for (int j = 0; j < 4; ++j) atomicAdd(&ws[slot + (wu << 2) + j], ps[j]);
    }
    // counts via ballot (wave 0 only)
    if (wu == 0) {
      float cnt = 0.0f;
      #pragma unroll
      for (int o = 0; o < 32; ++o) {
        float cc = (float)(__popcll(__ballot(j1 == o)) + __popcll(__ballot(j2 == o)));
        if (l == o) cnt = cc;
      }
      if (l < 32) atomicAdd(&ws[8192 + slot + l], cnt);
    }
  }

  // ---- epilogue: coalesced y writes; p/j broadcast via shuffle ----
  float* yb = y + ((size_t)b * 32 * 2048 + c0) * 128;
  #pragma unroll
  for (int rep = 0; rep < 4; ++rep) {
    int i   = (rep << 9) + tid;
    int row = i >> 5;                    // row whose chunk this thread writes
    int d4  = i & 31;                    // logical chunk
    float q1 = __shfl(p1, row, 64);
    float q2 = __shfl(p2, row, 64);
    int   jp = __shfl(jpack, row, 64);
    int i1 = jp & 255, i2 = (jp >> 8) & 255;
    int t = row >> 5, h = row & 31;
    const float4 A  = *reinterpret_cast<const float4*>(
        &Xs[(((t << 5) + i1) << 7) + ((d4 ^ i1) << 2)]);
    const float4 Bv = *reinterpret_cast<const float4*>(
        &Xs[(((t << 5) + i2) << 7) + ((d4 ^ i2) << 2)]);
    f32x4 o4;
    o4.x = q1 * A.x + q2 * Bv.x;
    o4.y = q1 * A.y + q2 * Bv.y;
    o4.z = q1 * A.z + q2 * Bv.z;
    o4.w = q1 * A.w + q2 * Bv.w;
    __builtin_nontemporal_store(o4,
        reinterpret_cast<f32x4*>(yb + ((size_t)h * 2048 + t) * 128 + (d4 << 2)));
  }
}

__global__ __launch_bounds__(256) void finalize_kernel(const float* __restrict__ ws,
                                                       float* __restrict__ out_aux) {
  __shared__ double redP[8][32];
  __shared__ double redC[8][32];
  const int o = threadIdx.x & 31;
  const int g = threadIdx.x >> 5;
  double sp = 0.0, sc = 0.0;
  for (int s = g; s < NSLOT; s += 8) {
    sp += (double)ws[s * 32 + o];
    sc += (double)ws[8192 + s * 32 + o];
  }
  redP[g][o] = sp;
  redC[g][o] = sc;
  __syncthreads();
  if (threadIdx.x == 0) {
    double aux = 0.0;
    const double nrows  = 524288.0;          // B*H*C
    const double ntotal = 1048576.0;         // nrows * K
    for (int oo = 0; oo < 32; ++oo) {
      double tp = 0.0, tc = 0.0;
      for (int gg = 0; gg < 8; ++gg) { tp += redP[gg][oo]; tc += redC[gg][oo]; }
      aux += (tp / nrows) * (tc / ntotal);
    }
    out_aux[0] = (float)(0.01 * 32.0 * aux);
  }
}

extern "C" void kernel_launch(void* const* d_in, const int* in_sizes, int n_in,
                              void* d_out, int out_size, void* d_ws, size_t ws_size,
                              hipStream_t stream) {
  const float* x = (const float*)d_in[0];
  const float* W = (const float*)d_in[1];
  float*  y   = (float*)d_out;
  float*  ws  = (float*)d_ws;
  double* wd2 = (double*)((char*)d_ws + 65536);

  prep_kernel<<<64, 256, 0, stream>>>(W, wd2, ws);
  moe_router_kernel<<<8192, 512, 0, stream>>>(x, wd2, y, ws);
  finalize_kernel<<<1, 256, 0, stream>>>(ws, y + (size_t)8 * 32 * 2048 * 128);
}